// Round 3
// baseline (287.348 us; speedup 1.0000x reference)
//
#include <hip/hip_runtime.h>

#define BS 24
#define CREP 16
#define HH 320
#define WW 320
#define HW (HH * WW)            // 102400
#define TOTAL (BS * HW)         // 2457600
#define NMP 4
#define NSEG 16
#define MOM 0.99f

#define K1_BLOCKS 600           // 600 blk * 256 thr * 4 groups * 4 px = TOTAL
#define TILE 2048               // pixels per accum block
#define NTILES (HW / TILE)      // 50
#define NBLK (BS * NTILES)      // 1200

typedef __attribute__((ext_vector_type(8))) short   bf16x8;
typedef __attribute__((ext_vector_type(4))) float   f32x4;
typedef __attribute__((ext_vector_type(4))) unsigned int u32x4;

// ---------------------------------------------------------------------------
// K0: detect cond layout (1-byte bools vs int32). Random 0/1 bytes make a u32
// word >1 with p=7/8; 256 words all <=1 has p = 8^-256.
// ---------------------------------------------------------------------------
__global__ void detect_cond_kernel(const unsigned int* __restrict__ cond_u32,
                                   int* __restrict__ flag) {
    bool big = false;
    for (int i = threadIdx.x; i < 256; i += 64)
        big |= (cond_u32[i] > 1u);
    unsigned long long b = __ballot(big);
    if (threadIdx.x == 0) flag[0] = (b != 0ull) ? 1 : 0;
}

// ---------------------------------------------------------------------------
// K1: per-pixel seg byte (255 = invalid) -> segmap, + exact count histogram.
// ---------------------------------------------------------------------------
__global__ __launch_bounds__(256) void segmap_kernel(
    const int* __restrict__ pmi,
    const int* __restrict__ tgt,
    const int* __restrict__ smask,
    const unsigned char* __restrict__ cond_b,
    const int* __restrict__ flag,
    unsigned int* __restrict__ segmap32,
    unsigned int* __restrict__ cnt_part)
{
    __shared__ unsigned int hist[NSEG];
    if (threadIdx.x < NSEG) hist[threadIdx.x] = 0u;
    __syncthreads();

    const int byte_layout = flag[0];
    const int4* tgt4  = (const int4*)tgt;
    const int4* cond4 = (const int4*)cond_b;
    const unsigned int* condb = (const unsigned int*)cond_b;

#pragma unroll
    for (int i = 0; i < 4; ++i) {
        const int g = blockIdx.x * 256 + threadIdx.x + i * (K1_BLOCKS * 256);
        const int p = g * 4;
        const int hw = p % HW;
        const int4 t4 = tgt4[g];
        const int4 s4 = *(const int4*)(smask + hw);
        int cc[4];
        if (byte_layout) {
            const unsigned int cb = condb[g];
            cc[0] = cb & 0xff; cc[1] = (cb >> 8) & 0xff;
            cc[2] = (cb >> 16) & 0xff; cc[3] = cb >> 24;
        } else {
            const int4 ci = cond4[g];
            cc[0] = ci.x; cc[1] = ci.y; cc[2] = ci.z; cc[3] = ci.w;
        }
        const int tt[4] = {t4.x, t4.y, t4.z, t4.w};
        const int ss[4] = {s4.x, s4.y, s4.z, s4.w};
        unsigned int packed = 0;
#pragma unroll
        for (int k = 0; k < 4; ++k) {
            int seg = 255;
            if (tt[k] != 0 && ss[k] == 1 && cc[k] != 0) {
                seg = tt[k] * NMP + pmi[(size_t)(p + k) * 4 + tt[k]];
                atomicAdd(&hist[seg], 1u);
            }
            packed |= (unsigned int)(seg & 0xff) << (8 * k);
        }
        segmap32[g] = packed;
    }
    __syncthreads();
    if (threadIdx.x < NSEG)
        cnt_part[(size_t)threadIdx.x * K1_BLOCKS + blockIdx.x] = hist[threadIdx.x];
}

// ---------------------------------------------------------------------------
// K2: segment-sum as MFMA. out[seg][ch] = sum_px onehot[seg][px] * rep[px][ch]
// A: onehot from segmap bytes (bf16 1.0/0.0), B: rep truncated to bf16.
// Lane l: A-row / B-col = l&15, k = (l>>4)*8 + j. No LDS in hot loop.
// ---------------------------------------------------------------------------
__global__ __launch_bounds__(256) void accum_kernel(
    const float* __restrict__ rep,
    const unsigned char* __restrict__ segmap,
    float* __restrict__ sum_part)
{
    const int b   = blockIdx.x / NTILES;
    const int hw0 = (blockIdx.x % NTILES) * TILE;
    const int tid = threadIdx.x;
    const int l   = tid & 63, wv = tid >> 6;
    const int ch  = l & 15, grp = l >> 4;

    const float* rbase = rep + ((size_t)b * CREP + ch) * HW + hw0 + grp * 8;
    const unsigned char* sbase = segmap + (size_t)b * HW + hw0 + grp * 8;
    const unsigned int chm = (unsigned int)ch;
    const unsigned int one = 0x3F80u;

    f32x4 acc = {0.f, 0.f, 0.f, 0.f};

#pragma unroll 2
    for (int it = wv * 32; it < TILE; it += 128) {
        const float4 v0 = *(const float4*)(rbase + it);
        const float4 v1 = *(const float4*)(rbase + it + 4);
        const unsigned int slo = *(const unsigned int*)(sbase + it);
        const unsigned int shi = *(const unsigned int*)(sbase + it + 4);

        u32x4 au, bu;
        au[0] = (((slo      ) & 0xff) == chm ? one : 0u) |
                (((slo >>  8) & 0xff) == chm ? one << 16 : 0u);
        au[1] = (((slo >> 16) & 0xff) == chm ? one : 0u) |
                (((slo >> 24) & 0xff) == chm ? one << 16 : 0u);
        au[2] = (((shi      ) & 0xff) == chm ? one : 0u) |
                (((shi >>  8) & 0xff) == chm ? one << 16 : 0u);
        au[3] = (((shi >> 16) & 0xff) == chm ? one : 0u) |
                (((shi >> 24) & 0xff) == chm ? one << 16 : 0u);

        bu[0] = (__float_as_uint(v0.x) >> 16) | (__float_as_uint(v0.y) & 0xffff0000u);
        bu[1] = (__float_as_uint(v0.z) >> 16) | (__float_as_uint(v0.w) & 0xffff0000u);
        bu[2] = (__float_as_uint(v1.x) >> 16) | (__float_as_uint(v1.y) & 0xffff0000u);
        bu[3] = (__float_as_uint(v1.z) >> 16) | (__float_as_uint(v1.w) & 0xffff0000u);

        acc = __builtin_amdgcn_mfma_f32_16x16x32_bf16(
            __builtin_bit_cast(bf16x8, au),
            __builtin_bit_cast(bf16x8, bu), acc, 0, 0, 0);
    }

    // merge 4 waves' C tiles via LDS; C layout: col=lane&15, row=(lane>>4)*4+r
    __shared__ float lacc[4][256];
#pragma unroll
    for (int r = 0; r < 4; ++r)
        lacc[wv][(grp * 4 + r) * 16 + ch] = acc[r];
    __syncthreads();
    if (tid < 256) {
        const float s = lacc[0][tid] + lacc[1][tid] + lacc[2][tid] + lacc[3][tid];
        sum_part[(size_t)tid * NBLK + blockIdx.x] = s;
    }
}

// ---------------------------------------------------------------------------
// K3: reduce partials + EMA.
// ---------------------------------------------------------------------------
__global__ __launch_bounds__(256) void reduce_kernel(
    const float* __restrict__ sum_part,
    const unsigned int* __restrict__ cnt_part,
    const float* __restrict__ protos,
    float* __restrict__ out)
{
    const int w    = (blockIdx.x * 256 + threadIdx.x) >> 6;  // 0..255
    const int lane = threadIdx.x & 63;
    const int seg  = w >> 4;

    float s = 0.f;
    for (int bb = lane; bb < NBLK; bb += 64)
        s += sum_part[(size_t)w * NBLK + bb];
    int cn = 0;
    for (int bb = lane; bb < K1_BLOCKS; bb += 64)
        cn += (int)cnt_part[(size_t)seg * K1_BLOCKS + bb];
#pragma unroll
    for (int off = 32; off > 0; off >>= 1) {
        s  += __shfl_xor(s, off, 64);
        cn += __shfl_xor(cn, off, 64);
    }
    if (lane == 0) {
        const float cnt  = (float)cn;
        const float mean = s / fmaxf(cnt, 1.0f);
        out[w] = (cn > 0) ? (MOM * protos[w] + (1.0f - MOM) * mean) : protos[w];
    }
}

extern "C" void kernel_launch(void* const* d_in, const int* in_sizes, int n_in,
                              void* d_out, int out_size, void* d_ws, size_t ws_size,
                              hipStream_t stream) {
    const float*         rep    = (const float*)d_in[0];
    const int*           pmi    = (const int*)d_in[1];
    const int*           tgt    = (const int*)d_in[2];
    const int*           smask  = (const int*)d_in[3];
    const unsigned char* cond   = (const unsigned char*)d_in[4];
    const float*         protos = (const float*)d_in[5];
    float*               out    = (float*)d_out;

    // ws layout (16B-aligned regions):
    //   [0, 2457600)            segmap (u8 per pixel)
    //   [2457600, 3686400)      sum_part  256 x NBLK f32
    //   [3686400, 3724800)      cnt_part  16 x K1_BLOCKS u32
    //   [3724800, +4)           flag
    unsigned char* ws      = (unsigned char*)d_ws;
    unsigned int* segmap32 = (unsigned int*)ws;
    float*        sum_part = (float*)(ws + (size_t)TOTAL);
    unsigned int* cnt_part = (unsigned int*)(ws + (size_t)TOTAL + 256 * NBLK * 4);
    int*          flag     = (int*)(ws + (size_t)TOTAL + 256 * NBLK * 4 + NSEG * K1_BLOCKS * 4);

    detect_cond_kernel<<<1, 64, 0, stream>>>((const unsigned int*)cond, flag);
    segmap_kernel<<<K1_BLOCKS, 256, 0, stream>>>(pmi, tgt, smask, cond, flag,
                                                 segmap32, cnt_part);
    accum_kernel<<<NBLK, 256, 0, stream>>>(rep, (const unsigned char*)segmap32,
                                           sum_part);
    reduce_kernel<<<64, 256, 0, stream>>>(sum_part, cnt_part, protos, out);
}

// Round 4
// 274.149 us; speedup vs baseline: 1.0481x; 1.0481x over previous
//
#include <hip/hip_runtime.h>

#define BS 24
#define CREP 16
#define HH 320
#define WW 320
#define HW (HH * WW)            // 102400
#define TOTAL (BS * HW)         // 2457600
#define NMP 4
#define NSEG 16
#define MOM 0.99f

#define TILE 2048               // pixels per block
#define NTILES (HW / TILE)      // 50
#define NBLK (BS * NTILES)      // 1200

typedef __attribute__((ext_vector_type(8))) short   bf16x8;
typedef __attribute__((ext_vector_type(4))) float   f32x4;
typedef __attribute__((ext_vector_type(4))) unsigned int u32x4;

// ---------------------------------------------------------------------------
// K0: detect cond layout (1-byte bools vs int32). Random 0/1 bytes make a u32
// word >1 with p=7/8; 256 words all <=1 has p = 8^-256.
// ---------------------------------------------------------------------------
__global__ void detect_cond_kernel(const unsigned int* __restrict__ cond_u32,
                                   int* __restrict__ flag) {
    bool big = false;
    for (int i = threadIdx.x; i < 256; i += 64)
        big |= (cond_u32[i] > 1u);
    unsigned long long b = __ballot(big);
    if (threadIdx.x == 0) flag[0] = (b != 0ull) ? 1 : 0;
}

// ---------------------------------------------------------------------------
// K1 (fused): phase 1 builds seg bytes in LDS + exact count histogram;
// phase 2 streams rep with 4-deep batched loads into MFMA segment-sums.
// out[seg][ch] = sum_px onehot[seg][px] * rep[px][ch] via mfma 16x16x32 bf16.
// ---------------------------------------------------------------------------
__global__ __launch_bounds__(256) void fused_kernel(
    const float* __restrict__ rep,
    const int* __restrict__ pmi,
    const int* __restrict__ tgt,
    const int* __restrict__ smask,
    const unsigned char* __restrict__ cond_b,
    const int* __restrict__ flag,
    float* __restrict__ sum_part,
    unsigned int* __restrict__ cnt_part)
{
    __shared__ unsigned int segp[TILE / 4];   // packed seg bytes, 4 px/word
    __shared__ unsigned int hist[NSEG];
    __shared__ float lacc[4][256];

    const int tid = threadIdx.x;
    if (tid < NSEG) hist[tid] = 0u;
    __syncthreads();

    const int b   = blockIdx.x / NTILES;
    const int hw0 = (blockIdx.x % NTILES) * TILE;
    const int p0  = b * HW + hw0;
    const int byte_layout = flag[0];

    // ---- phase 1: seg bytes -> LDS, counts -> hist ------------------------
    const int4* tgt4  = (const int4*)tgt;
    const int4* cond4 = (const int4*)cond_b;
    const unsigned int* condb = (const unsigned int*)cond_b;

#pragma unroll
    for (int j = 0; j < 2; ++j) {
        const int g  = tid + j * 256;          // int4 group within tile
        const int gg = (p0 >> 2) + g;          // global group
        const int4 t4 = tgt4[gg];
        const int4 s4 = *(const int4*)(smask + hw0 + g * 4);
        int cc[4];
        if (byte_layout) {
            const unsigned int cb = condb[gg];
            cc[0] = cb & 0xff; cc[1] = (cb >> 8) & 0xff;
            cc[2] = (cb >> 16) & 0xff; cc[3] = cb >> 24;
        } else {
            const int4 ci = cond4[gg];
            cc[0] = ci.x; cc[1] = ci.y; cc[2] = ci.z; cc[3] = ci.w;
        }
        const int tt[4] = {t4.x, t4.y, t4.z, t4.w};
        const int ss[4] = {s4.x, s4.y, s4.z, s4.w};
        unsigned int packed = 0;
#pragma unroll
        for (int k = 0; k < 4; ++k) {
            int seg = 255;
            if (tt[k] != 0 && ss[k] == 1 && cc[k] != 0) {
                seg = tt[k] * NMP + pmi[(size_t)(p0 + g * 4 + k) * 4 + tt[k]];
                atomicAdd(&hist[seg], 1u);
            }
            packed |= (unsigned int)(seg & 0xff) << (8 * k);
        }
        segp[g] = packed;
    }
    __syncthreads();

    // ---- phase 2: 4-deep batched rep loads -> MFMA ------------------------
    const int l   = tid & 63, wv = tid >> 6;
    const int ch  = l & 15, grp = l >> 4;      // B-col / A-row = ch; k-grp
    const float* rbase = rep + ((size_t)b * CREP + ch) * HW + hw0 + grp * 8;
    const unsigned char* sb = (const unsigned char*)segp;
    const unsigned int chm = (unsigned int)ch;
    const unsigned int one = 0x3F80u;

    f32x4 acc = {0.f, 0.f, 0.f, 0.f};

#pragma unroll 1
    for (int n = 0; n < 4; ++n) {              // 4 batches x 4 iters = 16
        float4 v0[4], v1[4];
        unsigned int slo[4], shi[4];
#pragma unroll
        for (int u = 0; u < 4; ++u) {
            const int it = wv * 32 + (n * 4 + u) * 128;
            v0[u] = *(const float4*)(rbase + it);
            v1[u] = *(const float4*)(rbase + it + 4);
            slo[u] = *(const unsigned int*)(sb + it + grp * 8);
            shi[u] = *(const unsigned int*)(sb + it + grp * 8 + 4);
        }
#pragma unroll
        for (int u = 0; u < 4; ++u) {
            u32x4 au, bu;
            au[0] = (((slo[u]      ) & 0xff) == chm ? one : 0u) |
                    (((slo[u] >>  8) & 0xff) == chm ? one << 16 : 0u);
            au[1] = (((slo[u] >> 16) & 0xff) == chm ? one : 0u) |
                    (((slo[u] >> 24) & 0xff) == chm ? one << 16 : 0u);
            au[2] = (((shi[u]      ) & 0xff) == chm ? one : 0u) |
                    (((shi[u] >>  8) & 0xff) == chm ? one << 16 : 0u);
            au[3] = (((shi[u] >> 16) & 0xff) == chm ? one : 0u) |
                    (((shi[u] >> 24) & 0xff) == chm ? one << 16 : 0u);

            bu[0] = (__float_as_uint(v0[u].x) >> 16) | (__float_as_uint(v0[u].y) & 0xffff0000u);
            bu[1] = (__float_as_uint(v0[u].z) >> 16) | (__float_as_uint(v0[u].w) & 0xffff0000u);
            bu[2] = (__float_as_uint(v1[u].x) >> 16) | (__float_as_uint(v1[u].y) & 0xffff0000u);
            bu[3] = (__float_as_uint(v1[u].z) >> 16) | (__float_as_uint(v1[u].w) & 0xffff0000u);

            acc = __builtin_amdgcn_mfma_f32_16x16x32_bf16(
                __builtin_bit_cast(bf16x8, au),
                __builtin_bit_cast(bf16x8, bu), acc, 0, 0, 0);
        }
    }

    // ---- merge 4 waves, write partials ------------------------------------
    // C layout (m89): col = lane&15 (=ch), row = (lane>>4)*4 + r (=seg)
#pragma unroll
    for (int r = 0; r < 4; ++r)
        lacc[wv][(grp * 4 + r) * 16 + ch] = acc[r];
    __syncthreads();

    const float s = lacc[0][tid] + lacc[1][tid] + lacc[2][tid] + lacc[3][tid];
    sum_part[(size_t)tid * NBLK + blockIdx.x] = s;
    if (tid < NSEG)
        cnt_part[(size_t)tid * NBLK + blockIdx.x] = hist[tid];
}

// ---------------------------------------------------------------------------
// K2: reduce partials + EMA.
// ---------------------------------------------------------------------------
__global__ __launch_bounds__(256) void reduce_kernel(
    const float* __restrict__ sum_part,
    const unsigned int* __restrict__ cnt_part,
    const float* __restrict__ protos,
    float* __restrict__ out)
{
    const int w    = (blockIdx.x * 256 + threadIdx.x) >> 6;  // 0..255
    const int lane = threadIdx.x & 63;
    const int seg  = w >> 4;

    float s = 0.f;
    int cn = 0;
    for (int bb = lane; bb < NBLK; bb += 64) {
        s  += sum_part[(size_t)w * NBLK + bb];
        cn += (int)cnt_part[(size_t)seg * NBLK + bb];
    }
#pragma unroll
    for (int off = 32; off > 0; off >>= 1) {
        s  += __shfl_xor(s, off, 64);
        cn += __shfl_xor(cn, off, 64);
    }
    if (lane == 0) {
        const float cnt  = (float)cn;
        const float mean = s / fmaxf(cnt, 1.0f);
        out[w] = (cn > 0) ? (MOM * protos[w] + (1.0f - MOM) * mean) : protos[w];
    }
}

extern "C" void kernel_launch(void* const* d_in, const int* in_sizes, int n_in,
                              void* d_out, int out_size, void* d_ws, size_t ws_size,
                              hipStream_t stream) {
    const float*         rep    = (const float*)d_in[0];
    const int*           pmi    = (const int*)d_in[1];
    const int*           tgt    = (const int*)d_in[2];
    const int*           smask  = (const int*)d_in[3];
    const unsigned char* cond   = (const unsigned char*)d_in[4];
    const float*         protos = (const float*)d_in[5];
    float*               out    = (float*)d_out;

    // ws layout: [sum_part 256*NBLK f32][cnt_part 16*NBLK u32][flag]
    unsigned char* ws      = (unsigned char*)d_ws;
    float*        sum_part = (float*)ws;
    unsigned int* cnt_part = (unsigned int*)(ws + (size_t)256 * NBLK * 4);
    int*          flag     = (int*)(ws + (size_t)256 * NBLK * 4 + (size_t)NSEG * NBLK * 4);

    detect_cond_kernel<<<1, 64, 0, stream>>>((const unsigned int*)cond, flag);
    fused_kernel<<<NBLK, 256, 0, stream>>>(rep, pmi, tgt, smask, cond, flag,
                                           sum_part, cnt_part);
    reduce_kernel<<<64, 256, 0, stream>>>(sum_part, cnt_part, protos, out);
}